// Round 2
// baseline (2277.181 us; speedup 1.0000x reference)
//
#include <hip/hip_runtime.h>
#include <hip/hip_bf16.h>
#include <cstdint>

// Problem constants (fixed by setup_inputs)
constexpr int NQ_     = 100000;
constexpr int NLLM_   = 20;
constexpr int NTOT_   = 100020;
constexpr int C_      = 192;
constexpr int HID_    = 64;
constexpr int K_      = 768;
constexpr int NUSER_  = 10;
constexpr int NUMEDGE_= 800000;
constexpr int NLLME_  = 380;
constexpr int NEI_    = 800380;   // edge_index columns
constexpr int NSEE_   = 600000;
constexpr int NMASKED_= NSEE_ + NLLME_;  // 600380
constexpr int NPRED_  = 200000;
constexpr float EPS_  = 1e-5f;

// ---- workspace layout (float offsets) ----
constexpr size_t WS_S1   = 0;              // 192
constexpr size_t WS_Q1   = 192;            // 192
constexpr size_t WS_S2   = 384;            // 192
constexpr size_t WS_Q2   = 576;            // 192
constexpr size_t WS_CNT  = 768;            // 20
constexpr size_t WS_SEW  = 788;            // 20
constexpr size_t WS_SX1  = 808;            // 3840
constexpr size_t WS_SX2  = 4648;           // 3840
constexpr size_t WS_ZERO_END = 8488;       // memset region [0, 8488)
constexpr size_t WS_U10  = 8488;           // 640
constexpr size_t WS_X1L  = 9128;           // 3840  x1 llm rows
constexpr size_t WS_X2L  = 12968;          // 3840  relu(bn1(x1)) llm rows
constexpr size_t WS_X2P  = 16808;          // 3840  conv2-out llm rows
constexpr size_t WS_A1   = 20648;          // 192
constexpr size_t WS_C1   = 20840;          // 192
constexpr size_t WS_Y    = 21032;          // 3840  bn2 output llm rows
constexpr size_t WS_XINI = 24872;          // NTOT_*C_ = 19,203,840

// ---------------- K0a: u10 = user_features @ W_user + b_user ----------------
__global__ void k_u10(const float* __restrict__ uf, const float* __restrict__ Wu,
                      const float* __restrict__ bu, float* __restrict__ u10) {
    int idx = blockIdx.x * blockDim.x + threadIdx.x;
    if (idx >= NUSER_ * HID_) return;
    int i = idx / HID_, h = idx % HID_;
    float acc = bu[h];
    for (int k = 0; k < 32; ++k) acc += uf[i * 32 + k] * Wu[k * HID_ + h];
    u10[idx] = acc;
}

// ---------------- K0b: x_ini llm rows = llm_features @ W_llm + b_llm --------
__global__ void k_llmrows(const float* __restrict__ llm, const float* __restrict__ Wl,
                          const float* __restrict__ bl, float* __restrict__ xini) {
    int d = blockIdx.x;          // 0..19
    int c = threadIdx.x;         // 0..191
    float acc = bl[c];
    const float* row = llm + (size_t)d * K_;
    for (int k = 0; k < K_; ++k) acc += row[k] * Wl[(size_t)k * C_ + c];
    xini[(size_t)(NQ_ + d) * C_ + c] = acc;
}

// ---------------- K1: x_ini rows 0..NQ  (t | q | u) -------------------------
// block 256 threads, 128-row tile; two 64-col GEMM halves (task,query), K=768
constexpr int TM_ = 128;
constexpr int KC_ = 32;
__global__ __launch_bounds__(256) void k_xini(
    const float* __restrict__ task, const float* __restrict__ query,
    const float* __restrict__ Wt, const float* __restrict__ bt,
    const float* __restrict__ Wq, const float* __restrict__ bq,
    const float* __restrict__ u10, float* __restrict__ xini)
{
    __shared__ float As[KC_][TM_];   // A transposed: [k][row]
    __shared__ float Ws[KC_][HID_];  // W: [k][col]
    int tid = threadIdx.x;
    int ty = tid >> 4, tx = tid & 15;          // 16x16 thread grid
    int s0 = blockIdx.x * TM_;

    for (int half = 0; half < 2; ++half) {
        const float* A = half ? query : task;
        const float* W = half ? Wq : Wt;
        const float* bias = half ? bq : bt;
        float acc[8][4];
        #pragma unroll
        for (int i = 0; i < 8; ++i)
            #pragma unroll
            for (int j = 0; j < 4; ++j) acc[i][j] = 0.f;

        for (int kc = 0; kc < K_; kc += KC_) {
            __syncthreads();
            // load A tile (128 rows x 32 k), store transposed
            {
                int row = tid >> 1;
                int ks  = (tid & 1) * 16;
                int gs  = s0 + row;
                float4 f4[4];
                if (gs < NQ_) {
                    const float4* p = reinterpret_cast<const float4*>(
                        A + (size_t)gs * K_ + kc + ks);
                    f4[0] = p[0]; f4[1] = p[1]; f4[2] = p[2]; f4[3] = p[3];
                } else {
                    f4[0] = f4[1] = f4[2] = f4[3] = make_float4(0.f, 0.f, 0.f, 0.f);
                }
                #pragma unroll
                for (int q4 = 0; q4 < 4; ++q4) {
                    As[ks + q4 * 4 + 0][row] = f4[q4].x;
                    As[ks + q4 * 4 + 1][row] = f4[q4].y;
                    As[ks + q4 * 4 + 2][row] = f4[q4].z;
                    As[ks + q4 * 4 + 3][row] = f4[q4].w;
                }
            }
            // load W tile (32 x 64)
            {
                #pragma unroll
                for (int q4 = 0; q4 < 2; ++q4) {
                    int fi = tid + q4 * 256;      // 512 float4s total
                    int k  = fi >> 4;
                    int c4 = (fi & 15) * 4;
                    float4 v = *reinterpret_cast<const float4*>(
                        W + (size_t)(kc + k) * HID_ + c4);
                    *reinterpret_cast<float4*>(&Ws[k][c4]) = v;
                }
            }
            __syncthreads();
            #pragma unroll
            for (int kk = 0; kk < KC_; ++kk) {
                float a[8], b[4];
                #pragma unroll
                for (int i = 0; i < 8; ++i) a[i] = As[kk][ty * 8 + i];
                #pragma unroll
                for (int j = 0; j < 4; ++j) b[j] = Ws[kk][tx * 4 + j];
                #pragma unroll
                for (int i = 0; i < 8; ++i)
                    #pragma unroll
                    for (int j = 0; j < 4; ++j) acc[i][j] += a[i] * b[j];
            }
        }
        int cbase = half * HID_ + tx * 4;
        #pragma unroll
        for (int i = 0; i < 8; ++i) {
            int gs = s0 + ty * 8 + i;
            if (gs < NQ_) {
                float4 v = make_float4(acc[i][0] + bias[tx * 4 + 0],
                                       acc[i][1] + bias[tx * 4 + 1],
                                       acc[i][2] + bias[tx * 4 + 2],
                                       acc[i][3] + bias[tx * 4 + 3]);
                *reinterpret_cast<float4*>(xini + (size_t)gs * C_ + cbase) = v;
            }
        }
    }
    // u columns (128..191): copy tiled u10 row
    {
        int cb = 128 + tx * 4;
        #pragma unroll
        for (int i = 0; i < 8; ++i) {
            int gs = s0 + ty * 8 + i;
            if (gs < NQ_) {
                int ur = gs % NUSER_;
                float4 v = *reinterpret_cast<const float4*>(u10 + ur * HID_ + tx * 4);
                *reinterpret_cast<float4*>(xini + (size_t)gs * C_ + cb) = v;
            }
        }
    }
}

// ---------------- K2: column sums/sumsq of x_ini rows < NQ ------------------
__global__ void k_colstats1(const float* __restrict__ xini,
                            float* __restrict__ S1, float* __restrict__ Q1) {
    int c = threadIdx.x;   // 192 threads
    float s = 0.f, q = 0.f;
    for (int r = blockIdx.x; r < NQ_; r += gridDim.x) {
        float v = xini[(size_t)r * C_ + c];
        s += v; q += v * v;
    }
    atomicAdd(&S1[c], s);
    atomicAdd(&Q1[c], q);
}

// ---------------- K3: edge pass 1 (cnt, sew, sum_x per dst) -----------------
__global__ __launch_bounds__(256) void k_edge1(
    const int* __restrict__ ei, const int* __restrict__ can_see,
    const float* __restrict__ ew, const float* __restrict__ Wemlp,
    const float* __restrict__ bemlp, const float* __restrict__ xini,
    float* __restrict__ sx1, float* __restrict__ cnt, float* __restrict__ sewg)
{
    __shared__ float lsx[NLLM_ * C_];
    __shared__ float lcnt[NLLM_], lsew[NLLM_];
    int tid = threadIdx.x;
    for (int i = tid; i < NLLM_ * C_; i += 256) lsx[i] = 0.f;
    if (tid < NLLM_) { lcnt[tid] = 0.f; lsew[tid] = 0.f; }
    __syncthreads();
    float we = Wemlp[0], be = bemlp[0];
    int lane = tid & 63;
    int wid  = (blockIdx.x * 256 + tid) >> 6;
    int nw   = (gridDim.x * 256) >> 6;
    int c0   = lane * 3;
    for (int j = wid; j < NMASKED_; j += nw) {
        int src, dst; float w;
        if (j < NSEE_) {
            int e = can_see[j];
            src = ei[e]; dst = ei[NEI_ + e];
            w = ew[e];
        } else {
            int e = NUMEDGE_ + (j - NSEE_);
            src = ei[e]; dst = ei[NEI_ + e];
            w = 1.f;
        }
        w = fmaxf(w * we + be, 0.f);
        int dl = dst - NQ_;
        if (lane == 0) { atomicAdd(&lcnt[dl], 1.f); atomicAdd(&lsew[dl], w); }
        const float* xr = xini + (size_t)src * C_ + c0;
        atomicAdd(&lsx[dl * C_ + c0 + 0], xr[0]);
        atomicAdd(&lsx[dl * C_ + c0 + 1], xr[1]);
        atomicAdd(&lsx[dl * C_ + c0 + 2], xr[2]);
    }
    __syncthreads();
    for (int i = tid; i < NLLM_ * C_; i += 256) atomicAdd(&sx1[i], lsx[i]);
    if (tid < NLLM_) { atomicAdd(&cnt[tid], lcnt[tid]); atomicAdd(&sewg[tid], lsew[tid]); }
}

// ---------------- K4: x1 llm rows = x_ini + agg1 ----------------------------
__global__ void k_llm1(const float* __restrict__ xini, const float* __restrict__ sx1,
                       const float* __restrict__ cnt, const float* __restrict__ sew,
                       const float* __restrict__ Wm, const float* __restrict__ bm,
                       const float* __restrict__ We, const float* __restrict__ be,
                       float* __restrict__ x1llm)
{
    int d = blockIdx.x, c = threadIdx.x;
    float acc = 0.f;
    for (int k = 0; k < C_; ++k) acc += sx1[d * C_ + k] * Wm[(size_t)k * C_ + c];
    float cd = cnt[d];
    acc += cd * bm[c] + sew[d] * We[c] + cd * be[c];
    x1llm[d * C_ + c] = acc + xini[(size_t)(NQ_ + d) * C_ + c];
}

// ---------------- K5: bn1 affine coefs + layer-2 input llm rows -------------
__global__ void k_stats1(const float* __restrict__ S1, const float* __restrict__ Q1,
                         const float* __restrict__ x1llm, const float* __restrict__ g1,
                         const float* __restrict__ beta1, float* __restrict__ a1,
                         float* __restrict__ c1, float* __restrict__ x2llm)
{
    int c = threadIdx.x;
    float s = S1[c], q = Q1[c];
    for (int d = 0; d < NLLM_; ++d) { float v = x1llm[d * C_ + c]; s += v; q += v * v; }
    float mu  = s / (float)NTOT_;
    float var = q / (float)NTOT_ - mu * mu;
    float rs  = rsqrtf(var + EPS_);
    float A   = rs * g1[c];
    float Cc  = beta1[c] - mu * A;
    a1[c] = A; c1[c] = Cc;
    for (int d = 0; d < NLLM_; ++d)
        x2llm[d * C_ + c] = fmaxf(x1llm[d * C_ + c] * A + Cc, 0.f);
}

// ---------------- K6: column stats of relu(bn1(x)) rows < NQ ----------------
__global__ void k_colstats2(const float* __restrict__ xini, const float* __restrict__ a1,
                            const float* __restrict__ c1,
                            float* __restrict__ S2, float* __restrict__ Q2) {
    int c = threadIdx.x;
    float A = a1[c], Cc = c1[c];
    float s = 0.f, q = 0.f;
    for (int r = blockIdx.x; r < NQ_; r += gridDim.x) {
        float v = fmaxf(xini[(size_t)r * C_ + c] * A + Cc, 0.f);
        s += v; q += v * v;
    }
    atomicAdd(&S2[c], s);
    atomicAdd(&Q2[c], q);
}

// ---------------- K7: edge pass 2 (sum of layer-2 input per dst) ------------
__global__ __launch_bounds__(256) void k_edge2(
    const int* __restrict__ ei, const int* __restrict__ can_see,
    const float* __restrict__ xini, const float* __restrict__ a1,
    const float* __restrict__ c1, const float* __restrict__ x2llm,
    float* __restrict__ sx2)
{
    __shared__ float lsx[NLLM_ * C_];
    int tid = threadIdx.x;
    for (int i = tid; i < NLLM_ * C_; i += 256) lsx[i] = 0.f;
    __syncthreads();
    int lane = tid & 63;
    int wid  = (blockIdx.x * 256 + tid) >> 6;
    int nw   = (gridDim.x * 256) >> 6;
    int c0   = lane * 3;
    float A0 = a1[c0], A1 = a1[c0 + 1], A2 = a1[c0 + 2];
    float C0 = c1[c0], C1 = c1[c0 + 1], C2 = c1[c0 + 2];
    for (int j = wid; j < NMASKED_; j += nw) {
        int src, dst;
        if (j < NSEE_) {
            int e = can_see[j];
            src = ei[e]; dst = ei[NEI_ + e];
        } else {
            int e = NUMEDGE_ + (j - NSEE_);
            src = ei[e]; dst = ei[NEI_ + e];
        }
        int dl = dst - NQ_;
        float v0, v1, v2;
        if (src < NQ_) {
            const float* xr = xini + (size_t)src * C_ + c0;
            v0 = fmaxf(xr[0] * A0 + C0, 0.f);
            v1 = fmaxf(xr[1] * A1 + C1, 0.f);
            v2 = fmaxf(xr[2] * A2 + C2, 0.f);
        } else {
            const float* xr = x2llm + (size_t)(src - NQ_) * C_ + c0;
            v0 = xr[0]; v1 = xr[1]; v2 = xr[2];
        }
        atomicAdd(&lsx[dl * C_ + c0 + 0], v0);
        atomicAdd(&lsx[dl * C_ + c0 + 1], v1);
        atomicAdd(&lsx[dl * C_ + c0 + 2], v2);
    }
    __syncthreads();
    for (int i = tid; i < NLLM_ * C_; i += 256) atomicAdd(&sx2[i], lsx[i]);
}

// ---------------- K8: conv2-out llm rows ------------------------------------
__global__ void k_llm2(const float* __restrict__ x2llm, const float* __restrict__ sx2,
                       const float* __restrict__ cnt, const float* __restrict__ sew,
                       const float* __restrict__ Wm, const float* __restrict__ bm,
                       const float* __restrict__ We, const float* __restrict__ be,
                       float* __restrict__ x2pre)
{
    int d = blockIdx.x, c = threadIdx.x;
    float acc = 0.f;
    for (int k = 0; k < C_; ++k) acc += sx2[d * C_ + k] * Wm[(size_t)k * C_ + c];
    float cd = cnt[d];
    acc += cd * bm[c] + sew[d] * We[c] + cd * be[c];
    x2pre[d * C_ + c] = acc + x2llm[d * C_ + c];
}

// ---------------- K9: bn2 -> y (llm rows only needed) -----------------------
__global__ void k_stats2(const float* __restrict__ S2, const float* __restrict__ Q2,
                         const float* __restrict__ x2pre, const float* __restrict__ g2,
                         const float* __restrict__ beta2, float* __restrict__ y)
{
    int c = threadIdx.x;
    float s = S2[c], q = Q2[c];
    for (int d = 0; d < NLLM_; ++d) { float v = x2pre[d * C_ + c]; s += v; q += v * v; }
    float mu  = s / (float)NTOT_;
    float var = q / (float)NTOT_ - mu * mu;
    float rs  = rsqrtf(var + EPS_);
    for (int d = 0; d < NLLM_; ++d)
        y[d * C_ + c] = (x2pre[d * C_ + c] - mu) * rs * g2[c] + beta2[c];
}

// ---------------- K10: prediction head --------------------------------------
__global__ __launch_bounds__(256) void k_out(
    const int* __restrict__ ei, const int* __restrict__ emask,
    const float* __restrict__ xini, const float* __restrict__ y,
    float* __restrict__ out)
{
    __shared__ float ys[NLLM_ * C_];
    int tid = threadIdx.x;
    for (int i = tid; i < NLLM_ * C_; i += 256) ys[i] = y[i];
    __syncthreads();
    int lane = tid & 63;
    int wid  = (blockIdx.x * 256 + tid) >> 6;
    int nw   = (gridDim.x * 256) >> 6;
    int c0   = lane * 3;
    for (int p = wid; p < NPRED_; p += nw) {
        int e  = emask[p];
        int sp = ei[e];
        int dp = ei[NEI_ + e] - NQ_;
        const float* xr = xini + (size_t)sp * C_ + c0;
        const float* yr = ys + dp * C_ + c0;
        float part = xr[0] * yr[0] + xr[1] * yr[1] + xr[2] * yr[2];
        #pragma unroll
        for (int off = 1; off < 64; off <<= 1) part += __shfl_xor(part, off);
        if (lane == 0) out[p] = 1.f / (1.f + expf(-part * (1.f / (float)C_)));
    }
}

// ============================================================================
extern "C" void kernel_launch(void* const* d_in, const int* in_sizes, int n_in,
                              void* d_out, int out_size, void* d_ws, size_t ws_size,
                              hipStream_t stream) {
    const float* task  = (const float*)d_in[0];
    const float* query = (const float*)d_in[1];
    const float* llm   = (const float*)d_in[2];
    const float* uf    = (const float*)d_in[3];
    const float* ew    = (const float*)d_in[4];
    const float* Wu    = (const float*)d_in[5];
    const float* bu    = (const float*)d_in[6];
    const float* Wq    = (const float*)d_in[7];
    const float* bq    = (const float*)d_in[8];
    const float* Wl    = (const float*)d_in[9];
    const float* bl    = (const float*)d_in[10];
    const float* Wt    = (const float*)d_in[11];
    const float* bt    = (const float*)d_in[12];
    const float* Wm1   = (const float*)d_in[13];
    const float* bm1   = (const float*)d_in[14];
    const float* We1   = (const float*)d_in[15];
    const float* be1   = (const float*)d_in[16];
    const float* Wm2   = (const float*)d_in[17];
    const float* bm2   = (const float*)d_in[18];
    const float* We2   = (const float*)d_in[19];
    const float* be2   = (const float*)d_in[20];
    const float* Wemlp = (const float*)d_in[21];
    const float* bemlp = (const float*)d_in[22];
    const float* g1    = (const float*)d_in[23];
    const float* beta1 = (const float*)d_in[24];
    const float* g2    = (const float*)d_in[25];
    const float* beta2 = (const float*)d_in[26];
    const int*   ei    = (const int*)d_in[27];
    const int*   csee  = (const int*)d_in[28];
    const int*   emask = (const int*)d_in[29];

    float* ws   = (float*)d_ws;
    float* S1   = ws + WS_S1;
    float* Q1   = ws + WS_Q1;
    float* S2   = ws + WS_S2;
    float* Q2   = ws + WS_Q2;
    float* cnt  = ws + WS_CNT;
    float* sew  = ws + WS_SEW;
    float* sx1  = ws + WS_SX1;
    float* sx2  = ws + WS_SX2;
    float* u10  = ws + WS_U10;
    float* x1l  = ws + WS_X1L;
    float* x2l  = ws + WS_X2L;
    float* x2p  = ws + WS_X2P;
    float* a1   = ws + WS_A1;
    float* c1   = ws + WS_C1;
    float* y    = ws + WS_Y;
    float* xini = ws + WS_XINI;
    float* outp = (float*)d_out;

    hipMemsetAsync(ws, 0, WS_ZERO_END * sizeof(float), stream);

    k_u10<<<3, 256, 0, stream>>>(uf, Wu, bu, u10);
    k_llmrows<<<NLLM_, C_, 0, stream>>>(llm, Wl, bl, xini);
    k_xini<<<(NQ_ + TM_ - 1) / TM_, 256, 0, stream>>>(task, query, Wt, bt, Wq, bq, u10, xini);
    k_colstats1<<<2048, C_, 0, stream>>>(xini, S1, Q1);
    k_edge1<<<2048, 256, 0, stream>>>(ei, csee, ew, Wemlp, bemlp, xini, sx1, cnt, sew);
    k_llm1<<<NLLM_, C_, 0, stream>>>(xini, sx1, cnt, sew, Wm1, bm1, We1, be1, x1l);
    k_stats1<<<1, C_, 0, stream>>>(S1, Q1, x1l, g1, beta1, a1, c1, x2l);
    k_colstats2<<<2048, C_, 0, stream>>>(xini, a1, c1, S2, Q2);
    k_edge2<<<2048, 256, 0, stream>>>(ei, csee, xini, a1, c1, x2l, sx2);
    k_llm2<<<NLLM_, C_, 0, stream>>>(x2l, sx2, cnt, sew, Wm2, bm2, We2, be2, x2p);
    k_stats2<<<1, C_, 0, stream>>>(S2, Q2, x2p, g2, beta2, y);
    k_out<<<2048, 256, 0, stream>>>(ei, emask, xini, y, outp);
}